// Round 18
// baseline (53.601 us; speedup 1.0000x reference)
//
#include <hip/hip_runtime.h>
#include <hip/hip_bf16.h>

#define NB 8
#define NT 2048
#define NC 1024
#define NH 64
#define NTP 2176   // padded V row stride (neutral, kept from r17)

typedef __attribute__((ext_vector_type(8))) short bf16x8;
typedef __attribute__((ext_vector_type(4))) short bf16x4;
typedef __attribute__((ext_vector_type(4))) float f32x4;

__device__ __forceinline__ unsigned short f2bf(float f) {
  __hip_bfloat16 h = __float2bfloat16(f);
  return __builtin_bit_cast(unsigned short, h);
}

__device__ __forceinline__ f32x4 mfma32(bf16x8 a, bf16x8 b, f32x4 c) {
  return __builtin_amdgcn_mfma_f32_16x16x32_bf16(a, b, c, 0, 0, 0);
}

#if __has_builtin(__builtin_amdgcn_mfma_f32_16x16x16bf16_1k)
__device__ __forceinline__ f32x4 mfma16(bf16x4 a, bf16x4 b, f32x4 c) {
  return __builtin_amdgcn_mfma_f32_16x16x16bf16_1k(a, b, c, 0, 0, 0);
}
#else
__device__ __forceinline__ f32x4 mfma16(bf16x4 a, bf16x4 b, f32x4 c) {
  asm volatile("v_mfma_f32_16x16x16_bf16 %0, %1, %2, %0\n\ts_nop 7"
               : "+v"(c) : "v"(a), "v"(b));
  return c;
}
#endif

// async global->LDS, 16B/lane; dst must be wave-uniform base (+lane*16 by HW)
__device__ __forceinline__ void stage16(const void* src, char* lds_base) {
#if __has_builtin(__builtin_amdgcn_global_load_lds)
  __builtin_amdgcn_global_load_lds(
      (const __attribute__((address_space(1))) void*)src,
      (__attribute__((address_space(3))) void*)lds_base, 16, 0, 0);
#endif
}

// ---------------------------------------------------------------------------
// Kernel 0: weight transpose+convert. W[1024][64] f32 -> Wt[64][1024] bf16.
// Folds softmax scale * log2(e) into Wq so attention can use exp2 directly.
// ---------------------------------------------------------------------------
__global__ __launch_bounds__(256) void wt_kernel(const float* __restrict__ Wq,
                                                 const float* __restrict__ Wk,
                                                 const float* __restrict__ Wv,
                                                 unsigned short* __restrict__ Wt) {
  __shared__ float lds[64][65];
  int wi = blockIdx.x >> 4, kt = blockIdx.x & 15;
  const float* W = (wi == 0) ? Wq : ((wi == 1) ? Wk : Wv);
  float scale = (wi == 0) ? 0.18033688011112043f : 1.0f;  // 0.125 * log2(e)
  int tid = threadIdx.x;
#pragma unroll
  for (int i = 0; i < 16; ++i) {
    int idx = tid + i * 256;
    lds[idx >> 6][idx & 63] = W[(size_t)(kt * 64 + (idx >> 6)) * NH + (idx & 63)] * scale;
  }
  __syncthreads();
#pragma unroll
  for (int i = 0; i < 16; ++i) {
    int idx = tid + i * 256;
    int n = idx >> 6, kk = idx & 63;
    Wt[(size_t)(wi * 64 + n) * NC + kt * 64 + kk] = f2bf(lds[kk][n]);
  }
}

// ---------------------------------------------------------------------------
// Kernel 1: fused QKV projection, v8.2 (EXACT r15-r17, ~24us). W staged to
// LDS one phase ahead via global_load_lds (pre-swizzled source, linear dest),
// x reg-staged bf16 one phase ahead. BM=32, BK=64, 16 phases, dbuf 56KB,
// 8 waves (wave = row-half x col-slice), W read from shared LDS.
// ---------------------------------------------------------------------------
__global__ __launch_bounds__(512) void proj_kernel(const float* __restrict__ x,
                                                   const unsigned short* __restrict__ Wt,
                                                   unsigned short* __restrict__ qo,
                                                   unsigned short* __restrict__ ko,
                                                   unsigned short* __restrict__ vo) {
  __shared__ __align__(16) char lds[57344];
  const int woff[2] = {0, 24576};
  const int xoff[2] = {49152, 53248};

  int tid = threadIdx.x;
  int lane = tid & 63, w = tid >> 6;      // 8 waves
  int ln = lane & 15, g = lane >> 4;
  int rf = w & 1;                          // row-half (16 rows)
  int cs = w >> 1;                         // col-slice (16 of 64)
  int row0 = blockIdx.x * 32;
  int nc = cs * 16 + ln;

  int srow = tid >> 4, si = tid & 15;
  const float* xsrc = x + (size_t)(row0 + srow) * NC + si * 4;
  int xwb = (srow * 128 + (((si >> 1) ^ (srow & 7)) << 4) + (si & 1) * 8);

  int wl_row = lane >> 3;
  int wl_sg = (lane & 7) ^ wl_row;

  f32x4 acc[3];
#pragma unroll
  for (int j = 0; j < 3; ++j) acc[j] = (f32x4){0.f, 0.f, 0.f, 0.f};

  float4 R0 = *(const float4*)(xsrc);
#pragma unroll
  for (int t = 0; t < 3; ++t) {
    int tt = w + t * 8;            // wave-uniform, 0..23
    int mat = tt >> 3, ii = tt & 7;
    stage16(Wt + (size_t)(mat * 64 + ii * 8 + wl_row) * NC + wl_sg * 8,
            lds + woff[0] + mat * 8192 + ii * 1024);
  }
  {
    bf16x4 b4;
    b4[0] = (short)f2bf(R0.x); b4[1] = (short)f2bf(R0.y);
    b4[2] = (short)f2bf(R0.z); b4[3] = (short)f2bf(R0.w);
    *(bf16x4*)(lds + xoff[0] + xwb) = b4;
  }
  R0 = *(const float4*)(xsrc + 64);
  __syncthreads();

#pragma unroll 1
  for (int p = 0; p < 16; ++p) {
    if (p < 15) {
#pragma unroll
      for (int t = 0; t < 3; ++t) {
        int tt = w + t * 8;
        int mat = tt >> 3, ii = tt & 7;
        stage16(Wt + (size_t)(mat * 64 + ii * 8 + wl_row) * NC + (p + 1) * 64 + wl_sg * 8,
                lds + woff[(p + 1) & 1] + mat * 8192 + ii * 1024);
      }
      bf16x4 b4;
      b4[0] = (short)f2bf(R0.x); b4[1] = (short)f2bf(R0.y);
      b4[2] = (short)f2bf(R0.z); b4[3] = (short)f2bf(R0.w);
      *(bf16x4*)(lds + xoff[(p + 1) & 1] + xwb) = b4;
    }
    if (p < 14) {
      R0 = *(const float4*)(xsrc + (p + 2) * 64);
    }
    const char* xc = lds + xoff[p & 1];
    const char* wc = lds + woff[p & 1];
#pragma unroll
    for (int c0 = 0; c0 < 64; c0 += 32) {
      int row = rf * 16 + ln;
      int axb = row * 128 + ((c0 * 2 + g * 16) ^ ((ln & 7) << 4));
      bf16x8 a = *(const bf16x8*)(xc + axb);
      int kg = (c0 >> 3) + g;
      int wb = nc * 128 + ((kg ^ (ln & 7)) << 4);
      bf16x8 bq = *(const bf16x8*)(wc + wb);
      bf16x8 bk = *(const bf16x8*)(wc + 8192 + wb);
      bf16x8 bv = *(const bf16x8*)(wc + 16384 + wb);
      acc[0] = mfma32(a, bq, acc[0]);
      acc[1] = mfma32(a, bk, acc[1]);
      acc[2] = mfma32(a, bv, acc[2]);
    }
    __syncthreads();
  }

  // ---- epilogue: q,k direct; v via LDS transpose (alias onto lds base)
  unsigned short(*vlds)[40] = (unsigned short(*)[40])lds;
#pragma unroll
  for (int r = 0; r < 4; ++r) {
    int row = row0 + rf * 16 + g * 4 + r;
    qo[(size_t)row * NH + nc] = f2bf(acc[0][r]);
    ko[(size_t)row * NH + nc] = f2bf(acc[1][r]);
    vlds[nc][rf * 16 + g * 4 + r] = f2bf(acc[2][r]);
  }
  __syncthreads();
  if (tid < 256) {
    int b = row0 / NT, t0b = row0 % NT;
    int hh = tid >> 2, ts = (tid & 3) * 8;
    *(bf16x8*)(vo + (size_t)(b * NH + hh) * NTP + t0b + ts) = *(const bf16x8*)&vlds[hh][ts];
  }
}

// ---------------------------------------------------------------------------
// Kernel 2: causal flash attention, v10 = fixed-max v9 at DOUBLE TLP,
// CONSTANT pipeline warmth. Chunk = 32 keys; 8-way key-split at stride 256
// (wave ks starts at ks*32): per-wave chunk count and K-prefetch distance
// IDENTICAL to the 26us v7, but 4096 waves = 4 waves/SIMD (2x latency-hiding
// pool). Per-chunk work halves (8 mfma32 + 16 mfma16 + 16 exp). Fixed-max
// fold = plain adds, two-stage (waves 4-7 -> slots, pairwise merge by 0-3,
// then 3 slots -> wave 0). 512 blocks x 512 thr, LDS 45.5KB -> 2 blocks/CU.
// ---------------------------------------------------------------------------
__global__ __launch_bounds__(512) void attn_kernel(const unsigned short* __restrict__ qw,
                                                   const unsigned short* __restrict__ kw,
                                                   const unsigned short* __restrict__ vw,
                                                   float* __restrict__ out) {
  __shared__ float mbuf[4][64][36];
  __shared__ float olds[32][68];

  int tid = threadIdx.x;
  int lane = tid & 63, ks = tid >> 6;     // 8 waves
  int ln = lane & 15, g = lane >> 4;
  int bid = blockIdx.x;
  int b = bid & 7;
  int s = bid >> 3;                       // 0..63
  int qtile = (s < 32) ? s : 95 - s;      // folded: CU slot pair sums const
  int t0 = qtile * 32;
  int tqA = t0 + ln, tqB = t0 + 16 + ln;

  const unsigned short* qpA = qw + (size_t)(b * NT + tqA) * NH + g * 8;
  const unsigned short* qpB = qw + (size_t)(b * NT + tqB) * NH + g * 8;
  bf16x8 qa0 = *(const bf16x8*)(qpA);
  bf16x8 qa1 = *(const bf16x8*)(qpA + 32);
  bf16x8 qb0 = *(const bf16x8*)(qpB);
  bf16x8 qb1 = *(const bf16x8*)(qpB + 32);

  const unsigned short* kb = kw + (size_t)b * NT * NH + g * 8;
  const unsigned short* vb = vw + (size_t)b * NH * NTP;

  f32x4 oaccA[4], oaccB[4];
#pragma unroll
  for (int i = 0; i < 4; ++i) {
    oaccA[i] = (f32x4){0.f, 0.f, 0.f, 0.f};
    oaccB[i] = (f32x4){0.f, 0.f, 0.f, 0.f};
  }
  float lA = 0.f, lB = 0.f;

  // prefetch first chunk's K (ks*32 <= 224 < NT, always in-bounds)
  bf16x8 kc0[2], kc1[2];
#pragma unroll
  for (int st = 0; st < 2; ++st) {
    const unsigned short* kp = kb + (size_t)(ks * 32 + st * 16 + ln) * NH;
    kc0[st] = *(const bf16x8*)(kp);
    kc1[st] = *(const bf16x8*)(kp + 32);
  }

  int send = t0 + 32;
#pragma unroll 1
  for (int s0 = ks * 32; s0 < send; s0 += 256) {
    // ---- V loads early (independent of the exp pass)
    bf16x4 va[4][2];
#pragma unroll
    for (int hf = 0; hf < 4; ++hf) {
      const unsigned short* vp = vb + (size_t)(hf * 16 + ln) * NTP + s0 + g * 4;
#pragma unroll
      for (int st = 0; st < 2; ++st) va[hf][st] = *(const bf16x4*)(vp + st * 16);
    }
    // ---- S^T = K x Q^T for both q-subtiles (K regs shared)
    f32x4 sA[2], sB[2];
#pragma unroll
    for (int st = 0; st < 2; ++st) {
      f32x4 a = (f32x4){0.f, 0.f, 0.f, 0.f};
      a = mfma32(kc0[st], qa0, a);
      a = mfma32(kc1[st], qa1, a);
      sA[st] = a;
      f32x4 c = (f32x4){0.f, 0.f, 0.f, 0.f};
      c = mfma32(kc0[st], qb0, c);
      c = mfma32(kc1[st], qb1, c);
      sB[st] = c;
    }
    // ---- prefetch next chunk's K (hidden under exp + PV)
    if (s0 + 256 < send) {
#pragma unroll
      for (int st = 0; st < 2; ++st) {
        const unsigned short* kp = kb + (size_t)(s0 + 256 + st * 16 + ln) * NH;
        kc0[st] = *(const bf16x8*)(kp);
        kc1[st] = *(const bf16x8*)(kp + 32);
      }
    }
    // ---- causal masks (wave-uniform outer branches)
    if (s0 + 31 > t0) {
#pragma unroll
      for (int st = 0; st < 2; ++st)
#pragma unroll
        for (int r = 0; r < 4; ++r)
          if (s0 + st * 16 + g * 4 + r > tqA) sA[st][r] = -1e30f;
    }
    if (s0 + 31 > t0 + 16) {
#pragma unroll
      for (int st = 0; st < 2; ++st)
#pragma unroll
        for (int r = 0; r < 4; ++r)
          if (s0 + st * 16 + g * 4 + r > tqB) sB[st][r] = -1e30f;
    }
    // ---- fixed-max exponentials: p = 2^s, lane-local partial sums
    bf16x4 pA[2], pB[2];
#pragma unroll
    for (int st = 0; st < 2; ++st)
#pragma unroll
      for (int r = 0; r < 4; ++r) {
        float p = exp2f(sA[st][r]);
        lA += p;
        pA[st][r] = (short)f2bf(p);
        float q2 = exp2f(sB[st][r]);
        lB += q2;
        pB[st][r] = (short)f2bf(q2);
      }

    // ---- PV from preloaded V regs (shared by both q-subtiles)
#pragma unroll
    for (int hf = 0; hf < 4; ++hf)
#pragma unroll
      for (int st = 0; st < 2; ++st) {
        oaccA[hf] = mfma16(va[hf][st], pA[st], oaccA[hf]);
        oaccB[hf] = mfma16(va[hf][st], pB[st], oaccB[hf]);
      }
  }

  // ---- reduce lane partials across the 4 g-groups (once, after the loop)
  lA += __shfl_xor(lA, 16);
  lA += __shfl_xor(lA, 32);
  lB += __shfl_xor(lB, 16);
  lB += __shfl_xor(lB, 32);

  // ---- two-stage fold of 8 key-split partials (plain adds, fixed-max)
  // stage 1: waves 4-7 publish; waves 0-3 merge partner ks+4
  if (ks >= 4) {
    float* d = mbuf[ks - 4][lane];
    d[0] = lA; d[1] = lB;
#pragma unroll
    for (int hf = 0; hf < 4; ++hf)
#pragma unroll
      for (int r = 0; r < 4; ++r) {
        d[2 + hf * 4 + r] = oaccA[hf][r];
        d[18 + hf * 4 + r] = oaccB[hf][r];
      }
  }
  __syncthreads();
  if (ks < 4) {
    const float* d = mbuf[ks][lane];
    lA += d[0]; lB += d[1];
#pragma unroll
    for (int hf = 0; hf < 4; ++hf)
#pragma unroll
      for (int r = 0; r < 4; ++r) {
        oaccA[hf][r] += d[2 + hf * 4 + r];
        oaccB[hf][r] += d[18 + hf * 4 + r];
      }
  }
  __syncthreads();
  // stage 2: waves 1-3 publish; wave 0 merges
  if (ks >= 1 && ks < 4) {
    float* d = mbuf[ks - 1][lane];
    d[0] = lA; d[1] = lB;
#pragma unroll
    for (int hf = 0; hf < 4; ++hf)
#pragma unroll
      for (int r = 0; r < 4; ++r) {
        d[2 + hf * 4 + r] = oaccA[hf][r];
        d[18 + hf * 4 + r] = oaccB[hf][r];
      }
  }
  __syncthreads();
  if (ks == 0) {
#pragma unroll
    for (int j = 0; j < 3; ++j) {
      const float* d = mbuf[j][lane];
      lA += d[0]; lB += d[1];
#pragma unroll
      for (int hf = 0; hf < 4; ++hf)
#pragma unroll
        for (int r = 0; r < 4; ++r) {
          oaccA[hf][r] += d[2 + hf * 4 + r];
          oaccB[hf][r] += d[18 + hf * 4 + r];
        }
    }
    float invA = 1.f / lA, invB = 1.f / lB;
#pragma unroll
    for (int hf = 0; hf < 4; ++hf)
#pragma unroll
      for (int r = 0; r < 4; ++r) {
        olds[ln][hf * 16 + g * 4 + r] = oaccA[hf][r] * invA;
        olds[16 + ln][hf * 16 + g * 4 + r] = oaccB[hf][r] * invB;
      }
  }
  __syncthreads();
  // ---- transposed store out[b][t][h]
  if (tid < 128) {
    int tl = tid >> 2, h0 = (tid & 3) * 16;
    size_t obase = (size_t)(b * NT + t0 + tl) * NH + h0;
#pragma unroll
    for (int vv = 0; vv < 4; ++vv) {
      float4 t4 = make_float4(olds[tl][h0 + vv * 4 + 0], olds[tl][h0 + vv * 4 + 1],
                              olds[tl][h0 + vv * 4 + 2], olds[tl][h0 + vv * 4 + 3]);
      *(float4*)(out + obase + vv * 4) = t4;
    }
  }
}

// ---------------------------------------------------------------------------
extern "C" void kernel_launch(void* const* d_in, const int* in_sizes, int n_in,
                              void* d_out, int out_size, void* d_ws, size_t ws_size,
                              hipStream_t stream) {
  const float* x  = (const float*)d_in[0];
  const float* Wq = (const float*)d_in[1];
  const float* Wk = (const float*)d_in[2];
  const float* Wv = (const float*)d_in[3];
  float* out = (float*)d_out;

  unsigned short* Wt = (unsigned short*)d_ws;
  unsigned short* q  = (unsigned short*)((char*)d_ws + (1 << 19));
  unsigned short* k  = q + (size_t)NB * NT * NH;
  unsigned short* v  = k + (size_t)NB * NT * NH;   // padded: [NB][NH][NTP]

  wt_kernel<<<48, 256, 0, stream>>>(Wq, Wk, Wv, Wt);
  proj_kernel<<<(NB * NT) / 32, 512, 0, stream>>>(x, Wt, q, k, v);
  attn_kernel<<<512, 512, 0, stream>>>(q, k, v, out);
}

// Round 19
// 41.607 us; speedup vs baseline: 1.2883x; 1.2883x over previous
//
#include <hip/hip_runtime.h>
#include <hip/hip_bf16.h>

#define NB 8
#define NT 2048
#define NC 1024
#define NH 64

typedef __attribute__((ext_vector_type(8))) short bf16x8;
typedef __attribute__((ext_vector_type(4))) short bf16x4;
typedef __attribute__((ext_vector_type(4))) float f32x4;

__device__ __forceinline__ unsigned short f2bf(float f) {
  __hip_bfloat16 h = __float2bfloat16(f);
  return __builtin_bit_cast(unsigned short, h);
}

__device__ __forceinline__ f32x4 mfma32(bf16x8 a, bf16x8 b, f32x4 c) {
  return __builtin_amdgcn_mfma_f32_16x16x32_bf16(a, b, c, 0, 0, 0);
}

#if __has_builtin(__builtin_amdgcn_mfma_f32_16x16x16bf16_1k)
__device__ __forceinline__ f32x4 mfma16(bf16x4 a, bf16x4 b, f32x4 c) {
  return __builtin_amdgcn_mfma_f32_16x16x16bf16_1k(a, b, c, 0, 0, 0);
}
#else
__device__ __forceinline__ f32x4 mfma16(bf16x4 a, bf16x4 b, f32x4 c) {
  asm volatile("v_mfma_f32_16x16x16_bf16 %0, %1, %2, %0\n\ts_nop 7"
               : "+v"(c) : "v"(a), "v"(b));
  return c;
}
#endif

// async global->LDS, 16B/lane; dst must be wave-uniform base (+lane*16 by HW)
__device__ __forceinline__ void stage16(const void* src, char* lds_base) {
#if __has_builtin(__builtin_amdgcn_global_load_lds)
  __builtin_amdgcn_global_load_lds(
      (const __attribute__((address_space(1))) void*)src,
      (__attribute__((address_space(3))) void*)lds_base, 16, 0, 0);
#endif
}

// ---------------------------------------------------------------------------
// Fragment-order layouts (the ONE change this round):
//  K: kf[b][tile=key/16][1024 ush]: pos = half(dim/32)*512 + (g*16+ln)*8 + j
//     holds (key=tile*16+ln, dim=half*32+g*8+j). attn kc load = base+lane*8,
//     64 lanes x 16B CONTIGUOUS 1KB = 8 fully-consumed lines (was 16 partial).
//  V: vf[b][tile=t/16][hf=h/16][256 ush]: pos = (g*16+ln)*4 + r holds
//     (t=tile*16+g*4+r, h=hf*16+ln). attn va load = base+lane*4, 512B
//     contiguous = 4 lines (was 16 partial). 3x fewer line-touches per chunk.
// ---------------------------------------------------------------------------

// ---------------------------------------------------------------------------
// Kernel 0: weight transpose+convert. W[1024][64] f32 -> Wt[64][1024] bf16.
// Folds softmax scale * log2(e) into Wq so attention can use exp2 directly.
// ---------------------------------------------------------------------------
__global__ __launch_bounds__(256) void wt_kernel(const float* __restrict__ Wq,
                                                 const float* __restrict__ Wk,
                                                 const float* __restrict__ Wv,
                                                 unsigned short* __restrict__ Wt) {
  __shared__ float lds[64][65];
  int wi = blockIdx.x >> 4, kt = blockIdx.x & 15;
  const float* W = (wi == 0) ? Wq : ((wi == 1) ? Wk : Wv);
  float scale = (wi == 0) ? 0.18033688011112043f : 1.0f;  // 0.125 * log2(e)
  int tid = threadIdx.x;
#pragma unroll
  for (int i = 0; i < 16; ++i) {
    int idx = tid + i * 256;
    lds[idx >> 6][idx & 63] = W[(size_t)(kt * 64 + (idx >> 6)) * NH + (idx & 63)] * scale;
  }
  __syncthreads();
#pragma unroll
  for (int i = 0; i < 16; ++i) {
    int idx = tid + i * 256;
    int n = idx >> 6, kk = idx & 63;
    Wt[(size_t)(wi * 64 + n) * NC + kt * 64 + kk] = f2bf(lds[kk][n]);
  }
}

// ---------------------------------------------------------------------------
// Kernel 1: fused QKV projection, v8.3 = r15-r17's v8.2 with fragment-order
// k/v epilogue stores (ONLY the epilogue addressing changed). W staged to
// LDS one phase ahead via global_load_lds, x reg-staged bf16 one phase
// ahead. BM=32, BK=64, 16 phases, dbuf 56KB, 8 waves.
// ---------------------------------------------------------------------------
__global__ __launch_bounds__(512) void proj_kernel(const float* __restrict__ x,
                                                   const unsigned short* __restrict__ Wt,
                                                   unsigned short* __restrict__ qo,
                                                   unsigned short* __restrict__ kf,
                                                   unsigned short* __restrict__ vf) {
  __shared__ __align__(16) char lds[57344];
  const int woff[2] = {0, 24576};
  const int xoff[2] = {49152, 53248};

  int tid = threadIdx.x;
  int lane = tid & 63, w = tid >> 6;      // 8 waves
  int ln = lane & 15, g = lane >> 4;
  int rf = w & 1;                          // row-half (16 rows)
  int cs = w >> 1;                         // col-slice (16 of 64)
  int row0 = blockIdx.x * 32;
  int nc = cs * 16 + ln;

  int srow = tid >> 4, si = tid & 15;
  const float* xsrc = x + (size_t)(row0 + srow) * NC + si * 4;
  int xwb = (srow * 128 + (((si >> 1) ^ (srow & 7)) << 4) + (si & 1) * 8);

  int wl_row = lane >> 3;
  int wl_sg = (lane & 7) ^ wl_row;

  f32x4 acc[3];
#pragma unroll
  for (int j = 0; j < 3; ++j) acc[j] = (f32x4){0.f, 0.f, 0.f, 0.f};

  float4 R0 = *(const float4*)(xsrc);
#pragma unroll
  for (int t = 0; t < 3; ++t) {
    int tt = w + t * 8;            // wave-uniform, 0..23
    int mat = tt >> 3, ii = tt & 7;
    stage16(Wt + (size_t)(mat * 64 + ii * 8 + wl_row) * NC + wl_sg * 8,
            lds + woff[0] + mat * 8192 + ii * 1024);
  }
  {
    bf16x4 b4;
    b4[0] = (short)f2bf(R0.x); b4[1] = (short)f2bf(R0.y);
    b4[2] = (short)f2bf(R0.z); b4[3] = (short)f2bf(R0.w);
    *(bf16x4*)(lds + xoff[0] + xwb) = b4;
  }
  R0 = *(const float4*)(xsrc + 64);
  __syncthreads();

#pragma unroll 1
  for (int p = 0; p < 16; ++p) {
    if (p < 15) {
#pragma unroll
      for (int t = 0; t < 3; ++t) {
        int tt = w + t * 8;
        int mat = tt >> 3, ii = tt & 7;
        stage16(Wt + (size_t)(mat * 64 + ii * 8 + wl_row) * NC + (p + 1) * 64 + wl_sg * 8,
                lds + woff[(p + 1) & 1] + mat * 8192 + ii * 1024);
      }
      bf16x4 b4;
      b4[0] = (short)f2bf(R0.x); b4[1] = (short)f2bf(R0.y);
      b4[2] = (short)f2bf(R0.z); b4[3] = (short)f2bf(R0.w);
      *(bf16x4*)(lds + xoff[(p + 1) & 1] + xwb) = b4;
    }
    if (p < 14) {
      R0 = *(const float4*)(xsrc + (p + 2) * 64);
    }
    const char* xc = lds + xoff[p & 1];
    const char* wc = lds + woff[p & 1];
#pragma unroll
    for (int c0 = 0; c0 < 64; c0 += 32) {
      int row = rf * 16 + ln;
      int axb = row * 128 + ((c0 * 2 + g * 16) ^ ((ln & 7) << 4));
      bf16x8 a = *(const bf16x8*)(xc + axb);
      int kg = (c0 >> 3) + g;
      int wb = nc * 128 + ((kg ^ (ln & 7)) << 4);
      bf16x8 bq = *(const bf16x8*)(wc + wb);
      bf16x8 bk = *(const bf16x8*)(wc + 8192 + wb);
      bf16x8 bv = *(const bf16x8*)(wc + 16384 + wb);
      acc[0] = mfma32(a, bq, acc[0]);
      acc[1] = mfma32(a, bk, acc[1]);
      acc[2] = mfma32(a, bv, acc[2]);
    }
    __syncthreads();
  }

  // ---- epilogue: q linear; k fragment-order; v via LDS transpose -> frag
  unsigned short(*vlds)[40] = (unsigned short(*)[40])lds;
  int bb = row0 >> 11;                       // batch
#pragma unroll
  for (int r = 0; r < 4; ++r) {
    int row = row0 + rf * 16 + g * 4 + r;
    int rib = row & 2047;                    // row within batch
    qo[(size_t)row * NH + nc] = f2bf(acc[0][r]);
    int koff = ((rib >> 4) << 10) + ((nc >> 5) << 9) + (((nc >> 3) & 3) << 7) +
               ((rib & 15) << 3) + (nc & 7);
    kf[(size_t)bb * 131072 + koff] = f2bf(acc[1][r]);
    vlds[nc][rf * 16 + g * 4 + r] = f2bf(acc[2][r]);
  }
  __syncthreads();
  if (tid < 256) {
    int t0b = row0 & 2047;
    int hh = tid >> 2, ts = (tid & 3) * 8;
    const unsigned short* src = &vlds[hh][ts];
    int t1 = t0b + ts;                       // multiple of 8
    size_t vbase = (size_t)bb * 131072 + ((size_t)(t1 >> 4) << 10) + ((hh >> 4) << 8);
    int g0 = (t1 & 15) >> 2;
    *(bf16x4*)(vf + vbase + ((g0 * 16 + (hh & 15)) << 2)) = *(const bf16x4*)src;
    *(bf16x4*)(vf + vbase + (((g0 + 1) * 16 + (hh & 15)) << 2)) = *(const bf16x4*)(src + 4);
  }
}

// ---------------------------------------------------------------------------
// Kernel 2: causal flash attention, v11 = r17's fixed-max v9 with
// FRAGMENT-ORDER K/V loads (the ONE change). kc = base+lane*8 (1KB
// contiguous, 8 lines); va = base+lane*4 (512B contiguous, 4 lines).
// Per-chunk line-touches 384 -> 128. All else identical (512 blocks x 256,
// wave = 32q as two subtiles sharing K/V, 4-way key-split, V early,
// K prefetch, fixed-max softmax, folded balance, b=bid&7 XCD residency).
// ---------------------------------------------------------------------------
__global__ __launch_bounds__(256) void attn_kernel(const unsigned short* __restrict__ qw,
                                                   const unsigned short* __restrict__ kf,
                                                   const unsigned short* __restrict__ vf,
                                                   float* __restrict__ out) {
  __shared__ float mbuf[3][64][36];
  __shared__ float olds[32][68];

  int tid = threadIdx.x;
  int lane = tid & 63, ks = tid >> 6;
  int ln = lane & 15, g = lane >> 4;
  int bid = blockIdx.x;
  int b = bid & 7;
  int s = bid >> 3;                       // 0..63
  int qtile = (s < 32) ? s : 95 - s;      // folded: CU slot pair sums const
  int t0 = qtile * 32;
  int tqA = t0 + ln, tqB = t0 + 16 + ln;

  const unsigned short* qpA = qw + (size_t)(b * NT + tqA) * NH + g * 8;
  const unsigned short* qpB = qw + (size_t)(b * NT + tqB) * NH + g * 8;
  bf16x8 qa0 = *(const bf16x8*)(qpA);
  bf16x8 qa1 = *(const bf16x8*)(qpA + 32);
  bf16x8 qb0 = *(const bf16x8*)(qpB);
  bf16x8 qb1 = *(const bf16x8*)(qpB + 32);

  const unsigned short* kfb = kf + (size_t)b * 131072;
  const unsigned short* vfb = vf + (size_t)b * 131072;

  f32x4 oaccA[4], oaccB[4];
#pragma unroll
  for (int i = 0; i < 4; ++i) {
    oaccA[i] = (f32x4){0.f, 0.f, 0.f, 0.f};
    oaccB[i] = (f32x4){0.f, 0.f, 0.f, 0.f};
  }
  float lA = 0.f, lB = 0.f;

  // prefetch first chunk's K: contiguous fragment tiles
  bf16x8 kc0[4], kc1[4];
#pragma unroll
  for (int st = 0; st < 4; ++st) {
    const unsigned short* kp = kfb + (size_t)((ks * 4) + st) * 1024 + lane * 8;
    kc0[st] = *(const bf16x8*)(kp);
    kc1[st] = *(const bf16x8*)(kp + 512);
  }

  int send = t0 + 32;
#pragma unroll 1
  for (int s0 = ks * 64; s0 < send; s0 += 256) {
    // ---- V loads early: fragment blocks, 512B contiguous each
    bf16x4 va[4][4];
#pragma unroll
    for (int st = 0; st < 4; ++st) {
      const unsigned short* vp = vfb + (size_t)((s0 >> 4) + st) * 1024 + lane * 4;
#pragma unroll
      for (int hf = 0; hf < 4; ++hf) va[hf][st] = *(const bf16x4*)(vp + hf * 256);
    }
    // ---- S^T = K x Q^T for both q-subtiles (K regs shared)
    f32x4 sA[4], sB[4];
#pragma unroll
    for (int st = 0; st < 4; ++st) {
      f32x4 a = (f32x4){0.f, 0.f, 0.f, 0.f};
      a = mfma32(kc0[st], qa0, a);
      a = mfma32(kc1[st], qa1, a);
      sA[st] = a;
      f32x4 c = (f32x4){0.f, 0.f, 0.f, 0.f};
      c = mfma32(kc0[st], qb0, c);
      c = mfma32(kc1[st], qb1, c);
      sB[st] = c;
    }
    // ---- prefetch next chunk's K (hidden under exp + PV)
    if (s0 + 256 < send) {
#pragma unroll
      for (int st = 0; st < 4; ++st) {
        const unsigned short* kp = kfb + (size_t)(((s0 + 256) >> 4) + st) * 1024 + lane * 8;
        kc0[st] = *(const bf16x8*)(kp);
        kc1[st] = *(const bf16x8*)(kp + 512);
      }
    }
    // ---- causal masks (wave-uniform outer branches)
    if (s0 + 63 > t0) {
#pragma unroll
      for (int st = 0; st < 4; ++st)
#pragma unroll
        for (int r = 0; r < 4; ++r)
          if (s0 + st * 16 + g * 4 + r > tqA) sA[st][r] = -1e30f;
    }
    if (s0 + 63 > t0 + 16) {
#pragma unroll
      for (int st = 0; st < 4; ++st)
#pragma unroll
        for (int r = 0; r < 4; ++r)
          if (s0 + st * 16 + g * 4 + r > tqB) sB[st][r] = -1e30f;
    }
    // ---- fixed-max exponentials: p = 2^s, lane-local partial sums
    bf16x4 pA[4], pB[4];
#pragma unroll
    for (int st = 0; st < 4; ++st)
#pragma unroll
      for (int r = 0; r < 4; ++r) {
        float p = exp2f(sA[st][r]);
        lA += p;
        pA[st][r] = (short)f2bf(p);
        float q2 = exp2f(sB[st][r]);
        lB += q2;
        pB[st][r] = (short)f2bf(q2);
      }

    // ---- PV from preloaded V regs (shared by both q-subtiles)
#pragma unroll
    for (int hf = 0; hf < 4; ++hf)
#pragma unroll
      for (int st = 0; st < 4; ++st) {
        oaccA[hf] = mfma16(va[hf][st], pA[st], oaccA[hf]);
        oaccB[hf] = mfma16(va[hf][st], pB[st], oaccB[hf]);
      }
  }

  // ---- reduce lane partials across the 4 g-groups (once, after the loop)
  lA += __shfl_xor(lA, 16);
  lA += __shfl_xor(lA, 32);
  lB += __shfl_xor(lB, 16);
  lB += __shfl_xor(lB, 32);

  // ---- fold the 4 key-split partials (plain sums; wave 0 accumulates)
  if (ks) {
    float* d = mbuf[ks - 1][lane];
    d[0] = lA; d[1] = lB;
#pragma unroll
    for (int hf = 0; hf < 4; ++hf)
#pragma unroll
      for (int r = 0; r < 4; ++r) {
        d[2 + hf * 4 + r] = oaccA[hf][r];
        d[18 + hf * 4 + r] = oaccB[hf][r];
      }
  }
  __syncthreads();
  if (ks == 0) {
#pragma unroll
    for (int j = 0; j < 3; ++j) {
      const float* d = mbuf[j][lane];
      lA += d[0];
      lB += d[1];
#pragma unroll
      for (int hf = 0; hf < 4; ++hf)
#pragma unroll
        for (int r = 0; r < 4; ++r) {
          oaccA[hf][r] += d[2 + hf * 4 + r];
          oaccB[hf][r] += d[18 + hf * 4 + r];
        }
    }
    float invA = 1.f / lA, invB = 1.f / lB;
#pragma unroll
    for (int hf = 0; hf < 4; ++hf)
#pragma unroll
      for (int r = 0; r < 4; ++r) {
        olds[ln][hf * 16 + g * 4 + r] = oaccA[hf][r] * invA;
        olds[16 + ln][hf * 16 + g * 4 + r] = oaccB[hf][r] * invB;
      }
  }
  __syncthreads();
  // ---- transposed store out[b][t][h]
  if (tid < 128) {
    int tl = tid >> 2, h0 = (tid & 3) * 16;
    size_t obase = (size_t)(b * NT + t0 + tl) * NH + h0;
#pragma unroll
    for (int vv = 0; vv < 4; ++vv) {
      float4 t4 = make_float4(olds[tl][h0 + vv * 4 + 0], olds[tl][h0 + vv * 4 + 1],
                              olds[tl][h0 + vv * 4 + 2], olds[tl][h0 + vv * 4 + 3]);
      *(float4*)(out + obase + vv * 4) = t4;
    }
  }
}

// ---------------------------------------------------------------------------
extern "C" void kernel_launch(void* const* d_in, const int* in_sizes, int n_in,
                              void* d_out, int out_size, void* d_ws, size_t ws_size,
                              hipStream_t stream) {
  const float* x  = (const float*)d_in[0];
  const float* Wq = (const float*)d_in[1];
  const float* Wk = (const float*)d_in[2];
  const float* Wv = (const float*)d_in[3];
  float* out = (float*)d_out;

  unsigned short* Wt = (unsigned short*)d_ws;
  unsigned short* q  = (unsigned short*)((char*)d_ws + (1 << 19));
  unsigned short* k  = q + (size_t)NB * NT * NH;   // fragment-order K
  unsigned short* v  = k + (size_t)NB * NT * NH;   // fragment-order V

  wt_kernel<<<48, 256, 0, stream>>>(Wq, Wk, Wv, Wt);
  proj_kernel<<<(NB * NT) / 32, 512, 0, stream>>>(x, Wt, q, k, v);
  attn_kernel<<<512, 256, 0, stream>>>(q, k, v, out);
}